// Round 10
// baseline (475.315 us; speedup 1.0000x reference)
//
#include <hip/hip_runtime.h>
#include <hip/hip_cooperative_groups.h>
#include <stdint.h>

namespace cg = cooperative_groups;

// Problem dims (fixed by reference)
#define BB 8
#define LL 4096
#define DD 1024
#define MM 2048
#define CC 16            // chunk length for the two-level scan
#define NC (MM / CC)     // 128 chunks
#define NBLK 1024        // cooperative grid: 4 blocks/CU on 256 CUs

// ---- workspace layout (bytes) ----
#define OFF_CIDX   0                                   // B*L i32    = 131072
#define OFF_DECAY  (OFF_CIDX   + (size_t)BB*LL*4)      // B*M  f32   = 65536
#define OFF_PPRE   (OFF_DECAY  + (size_t)BB*MM*4)      // B*M  f32   = 65536
#define OFF_A      (OFF_PPRE   + (size_t)BB*MM*4)      // B*NC f32   = 4096
#define OFF_HSTART (OFF_A      + (size_t)BB*NC*4)      // B*NC*D f32 = 4 MB
#define OFF_HLOC   (OFF_HSTART + (size_t)BB*NC*DD*4)   // B*M*D bf16 = 32 MB
#define WS_NEEDED  (OFF_HLOC   + (size_t)BB*MM*DD*2)

// ---- bf16 helpers (RNE, hand-rolled: exact bit semantics) ------------------
__device__ __forceinline__ unsigned short f2bf(float f) {
    union { float f; uint32_t u; } v; v.f = f;
    uint32_t r = v.u + 0x7FFFu + ((v.u >> 16) & 1u);
    return (unsigned short)(r >> 16);
}
__device__ __forceinline__ float bf2f(unsigned short h) {
    union { uint32_t u; float f; } v; v.u = ((uint32_t)h) << 16;
    return v.f;
}

// ============================================================================
// Fused cooperative kernel: prep -> localscan -> chunkscan -> output.
// 1024 blocks x 256 threads, all co-resident (4 blocks/CU).
// ============================================================================
__global__ __launch_bounds__(256, 4) void k_fused(
    const float* __restrict__ hid,      // (B,M,D) f32
    const float* __restrict__ residual, // (B,L,D) f32
    const void*  __restrict__ mask_raw, // (B,L) bool-ish
    const float* __restrict__ prob,     // (B,L) f32
    const int*   __restrict__ counts,   // (B,)
    const float* __restrict__ state,    // (B,D) f32
    float* __restrict__ out,            // (B,L,D) f32
    float* __restrict__ out_state,      // (B,D) f32
    int*   __restrict__ cidx,           // ws (B,L)
    float* __restrict__ decay,          // ws (B,M)
    float* __restrict__ ppre,           // ws (B,M)
    float* __restrict__ abuf,           // ws (B,NC)
    unsigned short* __restrict__ hloc,  // ws (B,M,D) bf16
    float* __restrict__ hstart)         // ws (B,NC,D)
{
    cg::grid_group grid = cg::this_grid();

    const int tid  = threadIdx.x;
    const int lane = tid & 63;
    const int wid  = tid >> 6;          // 0..3
    const int blk  = blockIdx.x;

    __shared__ float s_decay[MM];       // phase 1 (8 KB)
    __shared__ int   s_wsum[4];
    __shared__ int   s_flags[2];
    __shared__ float s_a[CC];           // phase 2

    // ========================= PHASE 1: prep (blocks 0..7) ==================
    if (blk < BB) {
        const int b = blk;

        // detect mask storage: scan first 32768 bytes (safe in all layouts)
        const uint32_t* w = (const uint32_t*)mask_raw;
        int lf32 = 0, lbool = 0;
        for (int i = tid; i < 8192; i += 256) {
            uint32_t v = w[i];
            if (v == 0x3F800000u) lf32 = 1;
            if (v & 0xFFFFFF00u)  lbool = 1;
        }
        if (tid == 0) { s_flags[0] = 0; s_flags[1] = 0; }
        for (int j = tid; j < MM; j += 256) s_decay[j] = 1.0f;
        __syncthreads();
        if (lf32)  s_flags[0] = 1;
        if (lbool) s_flags[1] = 1;
        __syncthreads();
        const int mode = s_flags[0] ? 2 : (s_flags[1] ? 1 : 0);

        auto rdmask = [&](int l) -> int {
            size_t idx = (size_t)b * LL + l;
            if (mode == 2) return ((const float*)mask_raw)[idx] != 0.0f;
            if (mode == 1) return ((const unsigned char*)mask_raw)[idx] != 0;
            return ((const int*)mask_raw)[idx] != 0;
        };

        // 16 mask elems per thread, bitmask
        const int l0 = tid * 16;
        int bits = 0;
        #pragma unroll
        for (int e = 0; e < 16; ++e)
            if (rdmask(l0 + e)) bits |= (1 << e);
        const int s = __popc(bits);

        // wave inclusive scan of per-thread sums
        int incl = s;
        #pragma unroll
        for (int off = 1; off < 64; off <<= 1) {
            int v = __shfl_up(incl, off);
            if (lane >= off) incl += v;
        }
        if (lane == 63) s_wsum[wid] = incl;
        __syncthreads();
        int woff = 0;
        #pragma unroll
        for (int k = 0; k < 4; ++k) woff += (k < wid) ? s_wsum[k] : 0;

        int cum = woff + incl - s;          // exclusive count before this thread
        #pragma unroll
        for (int e = 0; e < 16; ++e) {
            const int mbit = (bits >> e) & 1;
            cum += mbit;
            cidx[(size_t)b * LL + l0 + e] = cum - 1;
            if (mbit) {
                float v = 1.0f - prob[(size_t)b * LL + l0 + e];
                s_decay[cum - 1] = fminf(fmaxf(v, 0.f), 1.f);
            }
        }
        __syncthreads();

        for (int j = tid; j < MM; j += 256) decay[(size_t)b * MM + j] = s_decay[j];
        if (tid < NC) {
            float p = 1.0f;
            const int t0 = tid * CC;
            #pragma unroll
            for (int t = 0; t < CC; ++t) {
                p *= s_decay[t0 + t];
                ppre[(size_t)b * MM + t0 + t] = p;
            }
            abuf[b * NC + tid] = p;
        }
    }
    grid.sync();

    // ========================= PHASE 2: local scans =========================
    {
        const int c = blk & (NC - 1);       // 0..127
        const int b = blk >> 7;             // 0..7
        const int count = counts[b];
        const int tstart = c * CC;
        const int tend = min(CC, count - tstart);
        if (tend > 0) {
            if (tid < CC) s_a[tid] = decay[(size_t)b * MM + tstart + tid];
            __syncthreads();
            const int d4 = tid;
            const float4* x = (const float4*)(hid + ((size_t)b * MM + tstart) * DD) + d4;
            ushort4*      o = (ushort4*)(hloc + ((size_t)b * MM + tstart) * DD) + d4;
            float4 h = make_float4(0.f, 0.f, 0.f, 0.f);
            #pragma unroll 4
            for (int t = 0; t < tend; ++t) {
                const float a  = s_a[t];
                const float om = 1.0f - a;
                const float4 xv = x[(size_t)t * (DD / 4)];
                h.x = fmaf(a, h.x, om * xv.x);
                h.y = fmaf(a, h.y, om * xv.y);
                h.z = fmaf(a, h.z, om * xv.z);
                h.w = fmaf(a, h.w, om * xv.w);
                ushort4 u;
                u.x = f2bf(h.x); u.y = f2bf(h.y); u.z = f2bf(h.z); u.w = f2bf(h.w);
                o[(size_t)t * (DD / 4)] = u;
            }
        }
    }
    grid.sync();

    // ========================= PHASE 3: chunk scan (per-wave) ===============
    {
        const int gw = blk * 4 + wid;       // 0..4095
        #pragma unroll
        for (int rep = 0; rep < 2; ++rep) {
            const int task = gw + rep * 4096;   // 0..8191
            const int b  = task >> 10;
            const int ch = task & 1023;
            const int count = counts[b];

            const float2 a2 = ((const float2*)(abuf + (size_t)b * NC))[lane];
            const float a0 = a2.x, a1 = a2.y;
            const int t0 = (2 * lane) * CC;
            const int t1 = (2 * lane + 1) * CC;
            float e0 = 0.0f, e1 = 0.0f;
            if (t0 < count) e0 = bf2f(hloc[((size_t)b * MM + min(t0 + CC - 1, count - 1)) * DD + ch]);
            if (t1 < count) e1 = bf2f(hloc[((size_t)b * MM + min(t1 + CC - 1, count - 1)) * DD + ch]);

            float A = a1 * a0;
            float E = fmaf(a1, e0, e1);
            #pragma unroll
            for (int off = 1; off < 64; off <<= 1) {
                const float pa = __shfl_up(A, off);
                const float pe = __shfl_up(E, off);
                if (lane >= off) { E = fmaf(A, pe, E); A *= pa; }
            }
            float Qa = __shfl_up(A, 1);
            float Qe = __shfl_up(E, 1);
            if (lane == 0) { Qa = 1.0f; Qe = 0.0f; }

            const float st = state[(size_t)b * DD + ch];
            hstart[((size_t)b * NC + 2 * lane) * DD + ch] = fmaf(Qa, st, Qe);
            const float Ra = a0 * Qa;
            const float Re = fmaf(a0, Qe, e0);
            hstart[((size_t)b * NC + 2 * lane + 1) * DD + ch] = fmaf(Ra, st, Re);
            if (lane == 63) out_state[(size_t)b * DD + ch] = fmaf(A, st, E);
        }
    }
    grid.sync();

    // ========================= PHASE 4: output (4 rows / iter) ==============
    {
        const int b  = blk >> 7;            // 32 rows per block, same batch
        const int d4 = tid;
        const int row0 = blk * 32;          // first of 32 rows (b*L + l)
        #pragma unroll 2
        for (int it = 0; it < 8; ++it) {
            const int bl = row0 + it * 4;
            int   j[4];
            float4 r[4], v[4];
            #pragma unroll
            for (int k = 0; k < 4; ++k) {
                j[k] = cidx[bl + k];
                r[k] = ((const float4*)(residual + (size_t)(bl + k) * DD))[d4];
            }
            #pragma unroll
            for (int k = 0; k < 4; ++k) {
                v[k] = r[k];
                if (j[k] >= 0) {
                    const float p = ppre[(size_t)b * MM + j[k]];
                    const int   c = j[k] / CC;
                    const float4 hs = ((const float4*)(hstart + ((size_t)b * NC + c) * DD))[d4];
                    const ushort4 hu = ((const ushort4*)(hloc + ((size_t)b * MM + j[k]) * DD))[d4];
                    v[k].x = r[k].x + fmaf(p, hs.x, bf2f(hu.x));
                    v[k].y = r[k].y + fmaf(p, hs.y, bf2f(hu.y));
                    v[k].z = r[k].z + fmaf(p, hs.z, bf2f(hu.z));
                    v[k].w = r[k].w + fmaf(p, hs.w, bf2f(hu.w));
                }
            }
            #pragma unroll
            for (int k = 0; k < 4; ++k)
                ((float4*)(out + (size_t)(bl + k) * DD))[d4] = v[k];
        }
    }
}

// ============================================================================
extern "C" void kernel_launch(void* const* d_in, const int* in_sizes, int n_in,
                              void* d_out, int out_size, void* d_ws, size_t ws_size,
                              hipStream_t stream) {
    const float* hid    = (const float*)d_in[0];
    const float* res    = (const float*)d_in[1];
    const void*  msk    = d_in[2];
    const float* prob   = (const float*)d_in[3];
    const int*   counts = (const int*)d_in[4];
    const float* state  = (const float*)d_in[5];

    float* out       = (float*)d_out;
    float* out_state = out + (size_t)BB * LL * DD;

    if (ws_size < WS_NEEDED) return;

    char* ws = (char*)d_ws;
    int*            cidx   = (int*)           (ws + OFF_CIDX);
    float*          decay  = (float*)         (ws + OFF_DECAY);
    float*          ppre   = (float*)         (ws + OFF_PPRE);
    float*          abuf   = (float*)         (ws + OFF_A);
    float*          hstart = (float*)         (ws + OFF_HSTART);
    unsigned short* hloc   = (unsigned short*)(ws + OFF_HLOC);

    void* args[] = {
        (void*)&hid, (void*)&res, (void*)&msk, (void*)&prob,
        (void*)&counts, (void*)&state, (void*)&out, (void*)&out_state,
        (void*)&cidx, (void*)&decay, (void*)&ppre, (void*)&abuf,
        (void*)&hloc, (void*)&hstart
    };
    hipLaunchCooperativeKernel((const void*)k_fused, dim3(NBLK), dim3(256),
                               args, 0, stream);
}

// Round 11
// 99.243 us; speedup vs baseline: 4.7894x; 4.7894x over previous
//
#include <hip/hip_runtime.h>
#include <stdint.h>

// Problem dims (fixed by reference)
#define BB 8
#define LL 4096
#define DD 1024
#define MM 2048
#define CC 16            // chunk length for the two-level scan
#define NC (MM / CC)     // 128 chunks

// ---- workspace layout (bytes) ----
#define OFF_CIDX   0                                   // B*L i32    = 131072
#define OFF_DECAY  (OFF_CIDX   + (size_t)BB*LL*4)      // B*M  f32   = 65536
#define OFF_PPRE   (OFF_DECAY  + (size_t)BB*MM*4)      // B*M  f32   = 65536
#define OFF_A      (OFF_PPRE   + (size_t)BB*MM*4)      // B*NC f32   = 4096
#define OFF_HSTART (OFF_A      + (size_t)BB*NC*4)      // B*NC*D f32 = 4 MB
#define OFF_HLOC   (OFF_HSTART + (size_t)BB*NC*DD*4)   // B*M*D bf16 = 32 MB
#define WS_NEEDED  (OFF_HLOC   + (size_t)BB*MM*DD*2)

// ---- bf16 helpers (RNE, hand-rolled: exact bit semantics) ------------------
__device__ __forceinline__ unsigned short f2bf(float f) {
    union { float f; uint32_t u; } v; v.f = f;
    uint32_t r = v.u + 0x7FFFu + ((v.u >> 16) & 1u);
    return (unsigned short)(r >> 16);
}
__device__ __forceinline__ float bf2f(unsigned short h) {
    union { uint32_t u; float f; } v; v.u = ((uint32_t)h) << 16;
    return v.f;
}

// ============================================================================
// K1: per-batch mask cumsum, decay scatter, within-chunk prefix products.
// One block per batch; 1024 threads = 16 waves; shuffle-based scan.
// [round-6 verbatim]
// ============================================================================
__global__ __launch_bounds__(1024) void k_prep(
    const void* __restrict__ mask_raw,
    const float* __restrict__ prob,
    int* __restrict__ chunk_idx,      // (B,L)
    float* __restrict__ decay,        // (B,M)
    float* __restrict__ ppre,         // (B,M)
    float* __restrict__ abuf)         // (B,NC)
{
    const int b    = blockIdx.x;
    const int tid  = threadIdx.x;
    const int lane = tid & 63;
    const int wid  = tid >> 6;        // 0..15

    __shared__ int s_f32, s_bool;
    __shared__ int s_wsum[16];
    __shared__ int s_woff[17];
    __shared__ float s_decay[MM];

    // ---- detect mask storage: scan first 32768 bytes (safe in all layouts) --
    const uint32_t* w = (const uint32_t*)mask_raw;
    int lf32 = 0, lbool = 0;
    for (int i = tid; i < 8192; i += 1024) {
        uint32_t v = w[i];
        if (v == 0x3F800000u) lf32 = 1;          // a 1.0f word -> f32 storage
        if (v & 0xFFFFFF00u)  lbool = 1;         // nonzero high bytes -> 1-byte
    }
    if (tid == 0) { s_f32 = 0; s_bool = 0; s_woff[0] = 0; }
    for (int j = tid; j < MM; j += 1024) s_decay[j] = 1.0f;
    __syncthreads();
    if (lf32)  s_f32 = 1;
    if (lbool) s_bool = 1;
    __syncthreads();
    const int mode = s_f32 ? 2 : (s_bool ? 1 : 0);   // 2=f32, 1=byte, 0=int32

    auto rdmask = [&](int l) -> int {
        size_t idx = (size_t)b * LL + l;
        if (mode == 2) return ((const float*)mask_raw)[idx] != 0.0f;
        if (mode == 1) return ((const unsigned char*)mask_raw)[idx] != 0;
        return ((const int*)mask_raw)[idx] != 0;
    };

    const int l0 = tid * 4;
    const int m0 = rdmask(l0 + 0);
    const int m1 = rdmask(l0 + 1);
    const int m2 = rdmask(l0 + 2);
    const int m3 = rdmask(l0 + 3);
    const int s  = m0 + m1 + m2 + m3;

    // wave-level inclusive scan of per-thread sums (no barriers)
    int incl = s;
    #pragma unroll
    for (int off = 1; off < 64; off <<= 1) {
        int v = __shfl_up(incl, off);
        if (lane >= off) incl += v;
    }
    if (lane == 63) s_wsum[wid] = incl;
    __syncthreads();

    // wave 0 scans the 16 wave totals
    if (wid == 0) {
        int v = (lane < 16) ? s_wsum[lane] : 0;
        #pragma unroll
        for (int off = 1; off < 16; off <<= 1) {
            int u = __shfl_up(v, off);
            if (lane >= off) v += u;
        }
        if (lane < 16) s_woff[lane + 1] = v;
    }
    __syncthreads();

    const int excl = s_woff[wid] + incl - s;   // tokens before this thread's 4

    const int c0 = excl + m0;
    const int c1 = c0 + m1;
    const int c2 = c1 + m2;
    const int c3 = c2 + m3;

    chunk_idx[(size_t)b * LL + l0 + 0] = c0 - 1;
    chunk_idx[(size_t)b * LL + l0 + 1] = c1 - 1;
    chunk_idx[(size_t)b * LL + l0 + 2] = c2 - 1;
    chunk_idx[(size_t)b * LL + l0 + 3] = c3 - 1;

    // scatter decay = clamp(1-prob,0,1) at masked slots (into LDS)
    if (m0) { float v = 1.0f - prob[(size_t)b*LL + l0+0]; s_decay[c0-1] = fminf(fmaxf(v,0.f),1.f); }
    if (m1) { float v = 1.0f - prob[(size_t)b*LL + l0+1]; s_decay[c1-1] = fminf(fmaxf(v,0.f),1.f); }
    if (m2) { float v = 1.0f - prob[(size_t)b*LL + l0+2]; s_decay[c2-1] = fminf(fmaxf(v,0.f),1.f); }
    if (m3) { float v = 1.0f - prob[(size_t)b*LL + l0+3]; s_decay[c3-1] = fminf(fmaxf(v,0.f),1.f); }
    __syncthreads();

    for (int j = tid; j < MM; j += 1024) decay[(size_t)b * MM + j] = s_decay[j];
    if (tid < NC) {
        float p = 1.0f;
        const int t0 = tid * CC;
        #pragma unroll
        for (int t = 0; t < CC; ++t) {
            p *= s_decay[t0 + t];
            ppre[(size_t)b * MM + t0 + t] = p;
        }
        abuf[b * NC + tid] = p;
    }
}

// ============================================================================
// K2: per-chunk local EMA scans (zero init), all D channels; bf16 output.
// grid = (NC, B) = 1024 blocks, 256 threads, 4 channels per thread.
// [round-6 verbatim]
// ============================================================================
__global__ __launch_bounds__(256) void k_localscan(
    const float* __restrict__ hid,     // (B,M,D) f32
    const float* __restrict__ decay,   // (B,M)
    const int* __restrict__ counts,
    unsigned short* __restrict__ hloc) // (B,M,D) bf16
{
    const int c = blockIdx.x;
    const int b = blockIdx.y;
    const int count = counts[b];
    const int tstart = c * CC;
    const int tend = min(CC, count - tstart);
    if (tend <= 0) return;

    __shared__ float s_a[CC];
    if (threadIdx.x < CC) s_a[threadIdx.x] = decay[(size_t)b * MM + tstart + threadIdx.x];
    __syncthreads();

    const int d4 = threadIdx.x;
    const float4*  x = (const float4*)(hid + ((size_t)b * MM + tstart) * DD) + d4;
    ushort4*       o = (ushort4*)(hloc + ((size_t)b * MM + tstart) * DD) + d4;

    float4 h = make_float4(0.f, 0.f, 0.f, 0.f);
    #pragma unroll 4
    for (int t = 0; t < tend; ++t) {
        const float a  = s_a[t];
        const float om = 1.0f - a;
        const float4 xv = x[(size_t)t * (DD / 4)];
        h.x = fmaf(a, h.x, om * xv.x);
        h.y = fmaf(a, h.y, om * xv.y);
        h.z = fmaf(a, h.z, om * xv.z);
        h.w = fmaf(a, h.w, om * xv.w);
        ushort4 u;
        u.x = f2bf(h.x); u.y = f2bf(h.y); u.z = f2bf(h.z); u.w = f2bf(h.w);
        o[(size_t)t * (DD / 4)] = u;
    }
}

// ============================================================================
// K3: parallel (Kogge-Stone) scan over the 128 chunks -> chunk-start states
// and new_state. grid = (D/2, B); 256 threads = 128 chunks x 2 channels.
// [round-6 verbatim]
// ============================================================================
__global__ __launch_bounds__(256) void k_scan(
    const float* __restrict__ state,            // (B,D)
    const float* __restrict__ abuf,             // (B,NC)
    const unsigned short* __restrict__ hloc,    // (B,M,D) bf16
    const int* __restrict__ counts,
    float* __restrict__ hstart,                 // (B,NC,D)
    float* __restrict__ out_state)              // (B,D)
{
    const int g  = blockIdx.x;             // channel group of 2
    const int b  = blockIdx.y;
    const int tid = threadIdx.x;
    const int c  = tid >> 1;               // 0..127
    const int i  = tid & 1;
    const int ch = g * 2 + i;
    const int count = counts[b];
    const int tstart = c * CC;

    float a = abuf[b * NC + c];
    float e = 0.0f;
    if (tstart < count) {
        const int row = min(tstart + CC - 1, count - 1);
        e = bf2f(hloc[((size_t)b * MM + row) * DD + ch]);
    }

    __shared__ float s_a[NC];
    __shared__ float s_e[NC][2];

    for (int off = 1; off < NC; off <<= 1) {
        s_a[c] = a;              // 2 threads write the same value: benign
        s_e[c][i] = e;
        __syncthreads();
        if (c >= off) {
            const float ap = s_a[c - off];
            const float ep = s_e[c - off][i];
            e = fmaf(a, ep, e);
            a = a * ap;
        }
        __syncthreads();
    }
    s_a[c] = a;
    s_e[c][i] = e;
    __syncthreads();

    const float st = state[(size_t)b * DD + ch];
    const float hs = (c == 0) ? st : fmaf(s_a[c - 1], st, s_e[c - 1][i]);
    hstart[((size_t)b * NC + c) * DD + ch] = hs;
    if (c == NC - 1) out_state[(size_t)b * DD + ch] = fmaf(a, st, e);
}

// ============================================================================
// K4: output = residual + gathered EMA. GRID-STRIDED: 2048 blocks x 16
// consecutive rows each (G11: cap blocks, amortize dispatch). Inner 4-row
// batches for ILP; consecutive rows share j -> hloc/hstart L1/L2 reuse.
// 16 rows never cross a batch boundary (4096 % 16 == 0).
// ============================================================================
__global__ __launch_bounds__(256) void k_output(
    const float* __restrict__ residual,         // (B,L,D)
    const int* __restrict__ chunk_idx,          // (B,L)
    const float* __restrict__ ppre,             // (B,M)
    const float* __restrict__ hstart,           // (B,NC,D)
    const unsigned short* __restrict__ hloc,    // (B,M,D) bf16
    float* __restrict__ out)                    // (B,L,D)
{
    const int g    = blockIdx.x;        // 0..2047
    const int row0 = g * 16;            // first row (b*L + l), same batch
    const int b    = row0 >> 12;        // L = 4096
    const int d4   = threadIdx.x;

    #pragma unroll
    for (int it = 0; it < 4; ++it) {
        const int bl = row0 + it * 4;
        int    j[4];
        float4 r[4], v[4];
        #pragma unroll
        for (int k = 0; k < 4; ++k) {
            j[k] = chunk_idx[bl + k];
            r[k] = ((const float4*)(residual + (size_t)(bl + k) * DD))[d4];
        }
        #pragma unroll
        for (int k = 0; k < 4; ++k) {
            v[k] = r[k];
            if (j[k] >= 0) {
                const float p = ppre[(size_t)b * MM + j[k]];
                const int   c = j[k] / CC;
                const float4 hs = ((const float4*)(hstart + ((size_t)b * NC + c) * DD))[d4];
                const ushort4 hu = ((const ushort4*)(hloc + ((size_t)b * MM + j[k]) * DD))[d4];
                v[k].x = r[k].x + fmaf(p, hs.x, bf2f(hu.x));
                v[k].y = r[k].y + fmaf(p, hs.y, bf2f(hu.y));
                v[k].z = r[k].z + fmaf(p, hs.z, bf2f(hu.z));
                v[k].w = r[k].w + fmaf(p, hs.w, bf2f(hu.w));
            }
        }
        #pragma unroll
        for (int k = 0; k < 4; ++k)
            ((float4*)(out + (size_t)(bl + k) * DD))[d4] = v[k];
    }
}

// ============================================================================
extern "C" void kernel_launch(void* const* d_in, const int* in_sizes, int n_in,
                              void* d_out, int out_size, void* d_ws, size_t ws_size,
                              hipStream_t stream) {
    const float* hid    = (const float*)d_in[0];   // (B,M,D) f32
    const float* res    = (const float*)d_in[1];   // (B,L,D) f32
    const void*  msk    = d_in[2];                 // (B,L) bool-ish
    const float* prob   = (const float*)d_in[3];   // (B,L) f32
    const int*   counts = (const int*)d_in[4];     // (B,) i32
    const float* state  = (const float*)d_in[5];   // (B,D) f32

    float* out       = (float*)d_out;                       // (B,L,D)
    float* out_state = out + (size_t)BB * LL * DD;          // (B,D)

    if (ws_size < WS_NEEDED) return;

    char* ws = (char*)d_ws;
    int*            cidx   = (int*)           (ws + OFF_CIDX);
    float*          decay  = (float*)         (ws + OFF_DECAY);
    float*          ppre   = (float*)         (ws + OFF_PPRE);
    float*          abuf   = (float*)         (ws + OFF_A);
    float*          hstart = (float*)         (ws + OFF_HSTART);
    unsigned short* hloc   = (unsigned short*)(ws + OFF_HLOC);

    hipLaunchKernelGGL(k_prep, dim3(BB), dim3(1024), 0, stream,
                       msk, prob, cidx, decay, ppre, abuf);
    hipLaunchKernelGGL(k_localscan, dim3(NC, BB), dim3(256), 0, stream,
                       hid, decay, counts, hloc);
    hipLaunchKernelGGL(k_scan, dim3(DD / 2, BB), dim3(256), 0, stream,
                       state, abuf, hloc, counts, hstart, out_state);
    hipLaunchKernelGGL(k_output, dim3(BB * LL / 16), dim3(256), 0, stream,
                       res, cidx, ppre, hstart, hloc, out);
}